// Round 6
// baseline (155.468 us; speedup 1.0000x reference)
//
#include <hip/hip_runtime.h>
#include <math.h>

constexpr int B_ = 8192;
constexpr int N_ = 1024;
constexpr int NTHREADS = 256;
constexpr int NPART = B_ * 4;             // 4 wave-partials per block
constexpr float SCALE = 1.0f / ((float)B_ * (float)N_);

typedef float vfloat4 __attribute__((ext_vector_type(4)));

// R = Rx(a) @ Ry(b) @ Rz(c), row-major 3x3 (matches reference euler_to_matrix_xyz)
__device__ __forceinline__ void euler_to_mat(float a, float b, float c, float R[9]) {
    float ca = cosf(a), sa = sinf(a);
    float cb = cosf(b), sb = sinf(b);
    float cc = cosf(c), sc = sinf(c);
    R[0] = cb * cc;                R[1] = -cb * sc;               R[2] = sb;
    R[3] = ca * sc + sa * sb * cc; R[4] = ca * cc - sa * sb * sc; R[5] = -sa * cb;
    R[6] = sa * sc - ca * sb * cc; R[7] = sa * cc + ca * sb * sc; R[8] = ca * cb;
}

__device__ __forceinline__ void compute_M(const float* __restrict__ pred,
                                          const float* __restrict__ mode,
                                          const float* __restrict__ gt,
                                          int b, float M[9]) {
    float m1 = pred[b * 4 + 0], m2 = pred[b * 4 + 1];
    float m3 = pred[b * 4 + 2], m4 = pred[b * 4 + 3];
    float sgn = (mode[b] > 0.5f) ? 1.0f : -1.0f;
    float e2 = sgn * asinf(sqrtf(m3 * m3 / (m1 * m1 + m2 * m2 + m3 * m3)));
    float e3 = atan2f(m4, m3 / (sinf(e2) + 1e-9f));
    float tmp = cosf(e2) * cosf(e3);
    float e1 = atan2f(m2 / tmp, m1 / tmp);
    e3 = (e3 > 0.0f) ? e3 : (e3 + 6.2831854820251465f); // float32(2*pi)
    float P[9], G[9];
    euler_to_mat(e1, e2, e3, P);
    euler_to_mat(gt[b * 3 + 0], gt[b * 3 + 1], gt[b * 3 + 2], G);
    #pragma unroll
    for (int i = 0; i < 9; ++i) M[i] = P[i] - G[i];
}

// ---------- Phase 1: all-lanes-parallel M computation (8192 threads) ----------
__global__ __launch_bounds__(256)
void prep_M_kernel(const float* __restrict__ pred, const float* __restrict__ mode,
                   const float* __restrict__ gt, float* __restrict__ Mout) {
    int b = blockIdx.x * blockDim.x + threadIdx.x;
    if (b >= B_) return;
    float M[9];
    compute_M(pred, mode, gt, b, M);
    #pragma unroll
    for (int i = 0; i < 9; ++i) Mout[b * 9 + i] = M[i];
}

__device__ __forceinline__ float dist3(float px, float py, float pz, const float* M) {
    float dx = px * M[0] + py * M[3] + pz * M[6];
    float dy = px * M[1] + py * M[4] + pz * M[7];
    float dz = px * M[2] + py * M[5] + pz * M[8];
    return sqrtf(dx * dx + dy * dy + dz * dz);
}

// ---------- Phase 2: minimal-VGPR streaming kernel ----------
// One batch per block of 256 threads. M via wave-uniform load on const
// __restrict__ -> s_load path, M lives in SGPRs (VGPR budget ~30 -> 8
// waves/SIMD, 100% occupancy). 3 float4 loads at kernel top, no LDS, no
// barriers; per-wave reduce, 4 partial stores per block.
__global__ __launch_bounds__(NTHREADS)
void point_kernel(const float* __restrict__ point,   // (B,N,3)
                  const float* __restrict__ Mg,      // (B,9)
                  float* __restrict__ partial)       // (B*4,)
{
    const int b = blockIdx.x;
    const int t = threadIdx.x;

    // 3 consecutive float4s = 4 whole points; wave covers contiguous 3 KB.
    const vfloat4* gp = (const vfloat4*)(point + (size_t)b * (N_ * 3));
    vfloat4 p0 = gp[3 * t + 0];
    vfloat4 p1 = gp[3 * t + 1];
    vfloat4 p2 = gp[3 * t + 2];

    float M[9];
    const float* mg = Mg + (size_t)b * 9;   // wave-uniform -> scalar loads
    #pragma unroll
    for (int i = 0; i < 9; ++i) M[i] = mg[i];

    float local = dist3(p0.x, p0.y, p0.z, M)
                + dist3(p0.w, p1.x, p1.y, M)
                + dist3(p1.z, p1.w, p2.x, M)
                + dist3(p2.y, p2.z, p2.w, M);

    #pragma unroll
    for (int off = 32; off > 0; off >>= 1)
        local += __shfl_down(local, off, 64);
    if ((t & 63) == 0) partial[b * 4 + (t >> 6)] = local;
}

// ---------- Phase 3: reduce 32768 partials -> scalar (vectorized) ----------
__global__ __launch_bounds__(1024)
void reduce_kernel(const float* __restrict__ partial, float* __restrict__ out) {
    __shared__ float swave[1024 / 64];
    const int t = threadIdx.x;
    const vfloat4* p4 = (const vfloat4*)partial;
    float local = 0.0f;
    #pragma unroll
    for (int i = 0; i < NPART / 4 / 1024; ++i) {     // 8 float4 per thread
        vfloat4 v = p4[t + 1024 * i];
        local += v.x + v.y + v.z + v.w;
    }
    #pragma unroll
    for (int off = 32; off > 0; off >>= 1)
        local += __shfl_down(local, off, 64);
    if ((t & 63) == 0) swave[t >> 6] = local;
    __syncthreads();
    if (t == 0) {
        float s = 0.0f;
        #pragma unroll
        for (int i = 0; i < 1024 / 64; ++i) s += swave[i];
        out[0] = s * SCALE;
    }
}

// ---------- Fallback (ws too small): fused, redundant per-thread M ----------
__global__ __launch_bounds__(NTHREADS)
void fused_atomic(const float* __restrict__ pred, const float* __restrict__ mode,
                  const float* __restrict__ gt, const float* __restrict__ point,
                  float* __restrict__ out) {
    const int b = blockIdx.x;
    const int t = threadIdx.x;
    const vfloat4* gp = (const vfloat4*)(point + (size_t)b * (N_ * 3));
    vfloat4 p0 = gp[3 * t + 0];
    vfloat4 p1 = gp[3 * t + 1];
    vfloat4 p2 = gp[3 * t + 2];
    float M[9];
    compute_M(pred, mode, gt, b, M);
    float local = dist3(p0.x, p0.y, p0.z, M)
                + dist3(p0.w, p1.x, p1.y, M)
                + dist3(p1.z, p1.w, p2.x, M)
                + dist3(p2.y, p2.z, p2.w, M);
    #pragma unroll
    for (int off = 32; off > 0; off >>= 1)
        local += __shfl_down(local, off, 64);
    if ((t & 63) == 0) atomicAdd(out, local * SCALE);
}

extern "C" void kernel_launch(void* const* d_in, const int* in_sizes, int n_in,
                              void* d_out, int out_size, void* d_ws, size_t ws_size,
                              hipStream_t stream) {
    const float* pred  = (const float*)d_in[0];
    const float* mode  = (const float*)d_in[1];
    const float* gt    = (const float*)d_in[2];
    const float* point = (const float*)d_in[3];
    float* out = (float*)d_out;

    const size_t need = (size_t)(B_ * 9 + NPART) * sizeof(float);
    if (ws_size >= need) {
        float* Mg      = (float*)d_ws;
        float* partial = Mg + B_ * 9;
        prep_M_kernel<<<B_ / 256, 256, 0, stream>>>(pred, mode, gt, Mg);
        point_kernel<<<B_, NTHREADS, 0, stream>>>(point, Mg, partial);
        reduce_kernel<<<1, 1024, 0, stream>>>(partial, out);
    } else {
        (void)hipMemsetAsync(out, 0, sizeof(float), stream);
        fused_atomic<<<B_, NTHREADS, 0, stream>>>(pred, mode, gt, point, out);
    }
}